// Round 1
// baseline (1401.131 us; speedup 1.0000x reference)
//
#include <hip/hip_runtime.h>
#include <hip/hip_bf16.h>

// GCN 2-layer encoder: N=100000 nodes, E=3.2M edges, Fin=256, Fh=128, Fo=64.
// out = A_norm @ relu(A_norm @ (x@W1) + b1) @ W2 ... precisely:
//   h1 = x@W1 ; a1 = relu(A@h1 + b1) ; h2 = a1@W2 ; out = A@h2 + b2
// A includes self-loops with weight 1, symmetric sqrt-degree normalization.

#define FIN 256
#define FH  128
#define FO  64

// ---------------- histogram: count in-edges per dst, accumulate weighted degree
__global__ __launch_bounds__(256) void hist_kernel(
    const int* __restrict__ src, const int* __restrict__ dst,
    const float* __restrict__ w, int* __restrict__ cnt,
    float* __restrict__ degf, int E) {
  int e = blockIdx.x * 256 + threadIdx.x;
  if (e < E) {
    int d = dst[e];
    atomicAdd(&cnt[d], 1);
    atomicAdd(&degf[d], w[e]);
  }
}

// ---------------- exclusive scan of cnt -> rowptr (single block, 1024 threads)
__global__ __launch_bounds__(1024) void scan_kernel(
    const int* __restrict__ cnt, int* __restrict__ rowptr, int N) {
  __shared__ int buf[1024];
  __shared__ int carry_s;
  int t = threadIdx.x;
  if (t == 0) carry_s = 0;
  __syncthreads();
  for (int base = 0; base < N; base += 1024) {
    int idx = base + t;
    int v = (idx < N) ? cnt[idx] : 0;
    buf[t] = v;
    __syncthreads();
    // Hillis-Steele inclusive scan
    for (int off = 1; off < 1024; off <<= 1) {
      int y = 0;
      if (t >= off) y = buf[t - off];
      __syncthreads();
      buf[t] += y;
      __syncthreads();
    }
    int inc = buf[t];
    int c = carry_s;
    if (idx < N) rowptr[idx] = c + inc - v;  // exclusive
    __syncthreads();
    if (t == 1023) carry_s = c + buf[1023];
    __syncthreads();
  }
  if (t == 0) rowptr[N] = carry_s;
}

// ---------------- dinv[i] = rsqrt(1 + sum_w)  (self-loop weight 1 included)
__global__ __launch_bounds__(256) void dinv_kernel(float* __restrict__ degf, int N) {
  int i = blockIdx.x * 256 + threadIdx.x;
  if (i < N) degf[i] = rsqrtf(1.0f + degf[i]);
}

// ---------------- scatter edges into CSR order, precompute norm
__global__ __launch_bounds__(256) void scatter_kernel(
    const int* __restrict__ src, const int* __restrict__ dst,
    const float* __restrict__ w, const int* __restrict__ rowptr,
    int* __restrict__ cnt, const float* __restrict__ dinv,
    int* __restrict__ ssrc, float* __restrict__ snorm, int E) {
  int e = blockIdx.x * 256 + threadIdx.x;
  if (e < E) {
    int s = src[e], d = dst[e];
    float wv = w[e];
    int pos = rowptr[d] + atomicAdd(&cnt[d], 1);
    ssrc[pos] = s;
    snorm[pos] = dinv[s] * wv * dinv[d];
  }
}

// ---------------- GEMM1: H[N,128] = X[N,256] @ W[256,128]
__global__ __launch_bounds__(256) void gemm1_kernel(
    const float* __restrict__ X, const float* __restrict__ W,
    float* __restrict__ H, int N) {
  __shared__ __align__(16) float xs[64][17];
  __shared__ __align__(16) float ws[16 * FH];
  int tid = threadIdx.x;
  int row0 = blockIdx.x * 64;
  int tx = tid & 31;        // col group: cols tx*4 .. tx*4+3
  int ty = tid >> 5;        // row group: rows ty*8 .. ty*8+7
  float acc[8][4];
  #pragma unroll
  for (int i = 0; i < 8; ++i)
    #pragma unroll
    for (int j = 0; j < 4; ++j) acc[i][j] = 0.f;

  for (int k0 = 0; k0 < FIN; k0 += 16) {
    {
      int r = tid >> 2, kq = (tid & 3) * 4;
      int gr = row0 + r;
      float4 v = make_float4(0.f, 0.f, 0.f, 0.f);
      if (gr < N) v = *(const float4*)(X + (size_t)gr * FIN + k0 + kq);
      xs[r][kq + 0] = v.x; xs[r][kq + 1] = v.y;
      xs[r][kq + 2] = v.z; xs[r][kq + 3] = v.w;
    }
    {
      const float4* s4 = (const float4*)(W + (size_t)k0 * FH);
      float4* d4 = (float4*)ws;
      d4[tid] = s4[tid];
      d4[tid + 256] = s4[tid + 256];
    }
    __syncthreads();
    #pragma unroll
    for (int kk = 0; kk < 16; ++kk) {
      float xv[8];
      #pragma unroll
      for (int i = 0; i < 8; ++i) xv[i] = xs[ty * 8 + i][kk];
      float4 wv = *(const float4*)(&ws[kk * FH + tx * 4]);
      #pragma unroll
      for (int i = 0; i < 8; ++i) {
        acc[i][0] += xv[i] * wv.x; acc[i][1] += xv[i] * wv.y;
        acc[i][2] += xv[i] * wv.z; acc[i][3] += xv[i] * wv.w;
      }
    }
    __syncthreads();
  }
  #pragma unroll
  for (int i = 0; i < 8; ++i) {
    int gr = row0 + ty * 8 + i;
    if (gr < N) {
      float4 v = make_float4(acc[i][0], acc[i][1], acc[i][2], acc[i][3]);
      *(float4*)(H + (size_t)gr * FH + tx * 4) = v;
    }
  }
}

// ---------------- GEMM2: H2[N,64] = A1[N,128] @ W2[128,64]
__global__ __launch_bounds__(256) void gemm2_kernel(
    const float* __restrict__ A1, const float* __restrict__ W2,
    float* __restrict__ H2, int N) {
  __shared__ __align__(16) float xs[64][17];
  __shared__ __align__(16) float ws[16 * FO];
  int tid = threadIdx.x;
  int row0 = blockIdx.x * 64;
  int tx = tid & 15;        // cols tx*4..+3
  int ty = tid >> 4;        // rows ty*4..+3
  float acc[4][4];
  #pragma unroll
  for (int i = 0; i < 4; ++i)
    #pragma unroll
    for (int j = 0; j < 4; ++j) acc[i][j] = 0.f;

  for (int k0 = 0; k0 < FH; k0 += 16) {
    {
      int r = tid >> 2, kq = (tid & 3) * 4;
      int gr = row0 + r;
      float4 v = make_float4(0.f, 0.f, 0.f, 0.f);
      if (gr < N) v = *(const float4*)(A1 + (size_t)gr * FH + k0 + kq);
      xs[r][kq + 0] = v.x; xs[r][kq + 1] = v.y;
      xs[r][kq + 2] = v.z; xs[r][kq + 3] = v.w;
    }
    {
      const float4* s4 = (const float4*)(W2 + (size_t)k0 * FO);
      float4* d4 = (float4*)ws;
      d4[tid] = s4[tid];   // 16*64 = 1024 floats = 256 float4s
    }
    __syncthreads();
    #pragma unroll
    for (int kk = 0; kk < 16; ++kk) {
      float xv[4];
      #pragma unroll
      for (int i = 0; i < 4; ++i) xv[i] = xs[ty * 4 + i][kk];
      float4 wv = *(const float4*)(&ws[kk * FO + tx * 4]);
      #pragma unroll
      for (int i = 0; i < 4; ++i) {
        acc[i][0] += xv[i] * wv.x; acc[i][1] += xv[i] * wv.y;
        acc[i][2] += xv[i] * wv.z; acc[i][3] += xv[i] * wv.w;
      }
    }
    __syncthreads();
  }
  #pragma unroll
  for (int i = 0; i < 4; ++i) {
    int gr = row0 + ty * 4 + i;
    if (gr < N) {
      float4 v = make_float4(acc[i][0], acc[i][1], acc[i][2], acc[i][3]);
      *(float4*)(H2 + (size_t)gr * FO + tx * 4) = v;
    }
  }
}

// ---------------- aggregation layer 1: a1 = relu(A @ h1 + b1), 128 feats
// one wave (64 lanes) per node, float2 per lane
__global__ __launch_bounds__(256) void agg1_kernel(
    const float* __restrict__ H1, const int* __restrict__ ssrc,
    const float* __restrict__ snorm, const int* __restrict__ rowptr,
    const float* __restrict__ dinv, const float* __restrict__ b1,
    float* __restrict__ A1, int N) {
  int wid = (blockIdx.x * 256 + threadIdx.x) >> 6;
  int lane = threadIdx.x & 63;
  if (wid >= N) return;
  int p0 = rowptr[wid], p1 = rowptr[wid + 1];
  const float2* hv2 = (const float2*)H1;
  float2 acc = make_float2(0.f, 0.f);
  for (int p = p0; p < p1; ++p) {
    int s = ssrc[p];
    float nm = snorm[p];
    float2 hv = hv2[(size_t)s * 64 + lane];
    acc.x += nm * hv.x;
    acc.y += nm * hv.y;
  }
  float di = dinv[wid];
  float sn = di * di;
  float2 hs = hv2[(size_t)wid * 64 + lane];
  acc.x += sn * hs.x;
  acc.y += sn * hs.y;
  float2 bv = ((const float2*)b1)[lane];
  acc.x = fmaxf(acc.x + bv.x, 0.f);
  acc.y = fmaxf(acc.y + bv.y, 0.f);
  *(float2*)(A1 + (size_t)wid * FH + 2 * lane) = acc;
}

// ---------------- aggregation layer 2: out = A @ h2 + b2, 64 feats
__global__ __launch_bounds__(256) void agg2_kernel(
    const float* __restrict__ H2, const int* __restrict__ ssrc,
    const float* __restrict__ snorm, const int* __restrict__ rowptr,
    const float* __restrict__ dinv, const float* __restrict__ b2,
    float* __restrict__ OUT, int N) {
  int wid = (blockIdx.x * 256 + threadIdx.x) >> 6;
  int lane = threadIdx.x & 63;
  if (wid >= N) return;
  int p0 = rowptr[wid], p1 = rowptr[wid + 1];
  float acc = 0.f;
  for (int p = p0; p < p1; ++p) {
    int s = ssrc[p];
    float nm = snorm[p];
    acc += nm * H2[(size_t)s * FO + lane];
  }
  float di = dinv[wid];
  acc += di * di * H2[(size_t)wid * FO + lane];
  acc += b2[lane];
  OUT[(size_t)wid * FO + lane] = acc;
}

extern "C" void kernel_launch(void* const* d_in, const int* in_sizes, int n_in,
                              void* d_out, int out_size, void* d_ws, size_t ws_size,
                              hipStream_t stream) {
  const float* x  = (const float*)d_in[0];
  const int*   ei = (const int*)d_in[1];
  const float* ew = (const float*)d_in[2];
  const float* W1 = (const float*)d_in[3];
  const float* b1 = (const float*)d_in[4];
  const float* W2 = (const float*)d_in[5];
  const float* b2 = (const float*)d_in[6];
  float* out = (float*)d_out;

  const int N = in_sizes[0] / FIN;        // 100000
  const int E = in_sizes[2];              // 3200000
  const int* src = ei;                    // edge_index[0]
  const int* dst = ei + E;                // edge_index[1]

  // workspace layout (16B-aligned slices)
  char* ws = (char*)d_ws;
  float* h1     = (float*)(ws);                               // N*128 f32 (reused as h2)
  float* a1     = (float*)(ws + (size_t)N * FH * 4);          // N*128 f32
  int*   ssrc   = (int*)  (ws + (size_t)N * FH * 8);          // E int
  float* snorm  = (float*)(ws + (size_t)N * FH * 8 + (size_t)E * 4);      // E f32
  int*   rowptr = (int*)  (ws + (size_t)N * FH * 8 + (size_t)E * 8);      // N+1 int (pad to 16B)
  size_t rp_bytes = (((size_t)(N + 1) * 4) + 15) & ~(size_t)15;
  int*   cnt    = (int*)  ((char*)rowptr + rp_bytes);         // N int
  float* degf   = (float*)((char*)cnt + (size_t)N * 4);       // N f32 (becomes dinv)

  // 1. zero cnt + degf (adjacent)
  hipMemsetAsync(cnt, 0, (size_t)N * 8, stream);
  // 2. histogram + weighted degree
  hist_kernel<<<(E + 255) / 256, 256, 0, stream>>>(src, dst, ew, cnt, degf, E);
  // 3. exclusive scan -> rowptr
  scan_kernel<<<1, 1024, 0, stream>>>(cnt, rowptr, N);
  // 4. dinv = rsqrt(1 + deg)
  dinv_kernel<<<(N + 255) / 256, 256, 0, stream>>>(degf, N);
  // 5. re-zero cnt
  hipMemsetAsync(cnt, 0, (size_t)N * 4, stream);
  // 6. scatter into CSR with precomputed norm
  scatter_kernel<<<(E + 255) / 256, 256, 0, stream>>>(src, dst, ew, rowptr, cnt,
                                                      degf, ssrc, snorm, E);
  // 7. h1 = x @ W1
  gemm1_kernel<<<(N + 63) / 64, 256, 0, stream>>>(x, W1, h1, N);
  // 8. a1 = relu(A @ h1 + b1)
  agg1_kernel<<<(N * 64 + 255) / 256, 256, 0, stream>>>(h1, ssrc, snorm, rowptr,
                                                        degf, b1, a1, N);
  // 9. h2 = a1 @ W2  (h2 reuses h1 buffer)
  gemm2_kernel<<<(N + 63) / 64, 256, 0, stream>>>(a1, W2, h1, N);
  // 10. out = A @ h2 + b2
  agg2_kernel<<<(N * 64 + 255) / 256, 256, 0, stream>>>(h1, ssrc, snorm, rowptr,
                                                        degf, b2, out, N);
}

// Round 4
// 985.858 us; speedup vs baseline: 1.4212x; 1.4212x over previous
//
#include <hip/hip_runtime.h>
#include <hip/hip_bf16.h>

// GCN 2-layer encoder: N=100000 nodes, E=3.2M edges, Fin=256, Fh=128, Fo=64.
//   h1 = x@W1 ; a1 = relu(A@h1 + b1) ; h2 = a1@W2 ; out = A@h2 + b2
// A includes self-loops (w=1), symmetric rsqrt-degree normalization.
//
// R4 bisect: R2/R3 failed at ~5e-2 independent of storage precision ->
// logic bug in the shfl/half-wave agg (prime suspect) or 3-phase scan.
// This round: R1's PROVEN wave-uniform agg structure (+x2 unroll, dual
// accumulators), 3-phase scan kept, h1 fp16 (model: ~1e-4 at output),
// h2 f32. Pass => shfl-agg was the bug; fail ~5e-2 => scan is the bug.

#define FIN 256
#define FH  128
#define FO  64

__device__ __forceinline__ float h2f(unsigned int u16) {
  union { unsigned short s; _Float16 h; } c; c.s = (unsigned short)u16;
  return (float)c.h;
}
__device__ __forceinline__ unsigned int f2h(float f) {
  union { _Float16 h; unsigned short s; } c; c.h = (_Float16)f;  // RNE cvt
  return (unsigned int)c.s;
}

// ---------------- histogram: count in-edges per dst, accumulate weighted degree
__global__ __launch_bounds__(256) void hist_kernel(
    const int* __restrict__ src, const int* __restrict__ dst,
    const float* __restrict__ w, int* __restrict__ cnt,
    float* __restrict__ degf, int E) {
  int e = blockIdx.x * 256 + threadIdx.x;
  if (e < E) {
    int d = dst[e];
    atomicAdd(&cnt[d], 1);
    atomicAdd(&degf[d], w[e]);
  }
}

// ---------------- 3-phase exclusive scan of cnt -> rowptr
__global__ __launch_bounds__(256) void scan1_kernel(
    const int* __restrict__ cnt, int* __restrict__ rowptr,
    int* __restrict__ bsum, int N) {
  __shared__ int tot[256];
  int t = threadIdx.x;
  int base = blockIdx.x * 1024 + t * 4;
  int v0 = (base + 0 < N) ? cnt[base + 0] : 0;
  int v1 = (base + 1 < N) ? cnt[base + 1] : 0;
  int v2 = (base + 2 < N) ? cnt[base + 2] : 0;
  int v3 = (base + 3 < N) ? cnt[base + 3] : 0;
  int s = v0 + v1 + v2 + v3;
  tot[t] = s;
  __syncthreads();
  for (int off = 1; off < 256; off <<= 1) {
    int y = (t >= off) ? tot[t - off] : 0;
    __syncthreads();
    tot[t] += y;
    __syncthreads();
  }
  int p = tot[t] - s;  // exclusive within block
  if (t == 255) bsum[blockIdx.x] = tot[255];
  if (base + 0 < N) rowptr[base + 0] = p; p += v0;
  if (base + 1 < N) rowptr[base + 1] = p; p += v1;
  if (base + 2 < N) rowptr[base + 2] = p; p += v2;
  if (base + 3 < N) rowptr[base + 3] = p;
}

__global__ __launch_bounds__(256) void scan2_kernel(
    int* __restrict__ bsum, int* __restrict__ rowptrN, int nb, int E) {
  __shared__ int buf[256];
  int t = threadIdx.x;
  int v = (t < nb) ? bsum[t] : 0;
  buf[t] = v;
  __syncthreads();
  for (int off = 1; off < 256; off <<= 1) {
    int y = (t >= off) ? buf[t - off] : 0;
    __syncthreads();
    buf[t] += y;
    __syncthreads();
  }
  if (t < nb) bsum[t] = buf[t] - v;  // exclusive
  if (t == 0) rowptrN[0] = E;
}

__global__ __launch_bounds__(256) void scan3_kernel(
    int* __restrict__ rowptr, const int* __restrict__ bsum, int N) {
  int i = blockIdx.x * 256 + threadIdx.x;
  if (i < N) rowptr[i] += bsum[i >> 10];
}

// ---------------- dinv[i] = rsqrt(1 + sum_w)
__global__ __launch_bounds__(256) void dinv_kernel(float* __restrict__ degf, int N) {
  int i = blockIdx.x * 256 + threadIdx.x;
  if (i < N) degf[i] = rsqrtf(1.0f + degf[i]);
}

// ---------------- scatter edges into CSR order, precompute norm
__global__ __launch_bounds__(256) void scatter_kernel(
    const int* __restrict__ src, const int* __restrict__ dst,
    const float* __restrict__ w, const int* __restrict__ rowptr,
    int* __restrict__ cnt, const float* __restrict__ dinv,
    int* __restrict__ ssrc, float* __restrict__ snorm, int E) {
  int e = blockIdx.x * 256 + threadIdx.x;
  if (e < E) {
    int s = src[e], d = dst[e];
    float wv = w[e];
    int pos = rowptr[d] + atomicAdd(&cnt[d], 1);
    ssrc[pos] = s;
    snorm[pos] = dinv[s] * wv * dinv[d];
  }
}

// ---------------- GEMM1: H1h[N,128](fp16) = X[N,256] @ W[256,128]
__global__ __launch_bounds__(256) void gemm1_kernel(
    const float* __restrict__ X, const float* __restrict__ W,
    unsigned short* __restrict__ H1h, int N) {
  __shared__ __align__(16) float xs[64][17];
  __shared__ __align__(16) float ws[16 * FH];
  int tid = threadIdx.x;
  int row0 = blockIdx.x * 64;
  int tx = tid & 31;        // cols tx*4 .. +3
  int ty = tid >> 5;        // rows ty*8 .. +7
  float acc[8][4];
  #pragma unroll
  for (int i = 0; i < 8; ++i)
    #pragma unroll
    for (int j = 0; j < 4; ++j) acc[i][j] = 0.f;

  for (int k0 = 0; k0 < FIN; k0 += 16) {
    {
      int r = tid >> 2, kq = (tid & 3) * 4;
      int gr = row0 + r;
      float4 v = make_float4(0.f, 0.f, 0.f, 0.f);
      if (gr < N) v = *(const float4*)(X + (size_t)gr * FIN + k0 + kq);
      xs[r][kq + 0] = v.x; xs[r][kq + 1] = v.y;
      xs[r][kq + 2] = v.z; xs[r][kq + 3] = v.w;
    }
    {
      const float4* s4 = (const float4*)(W + (size_t)k0 * FH);
      float4* d4 = (float4*)ws;
      d4[tid] = s4[tid];
      d4[tid + 256] = s4[tid + 256];
    }
    __syncthreads();
    #pragma unroll
    for (int kk = 0; kk < 16; ++kk) {
      float xv[8];
      #pragma unroll
      for (int i = 0; i < 8; ++i) xv[i] = xs[ty * 8 + i][kk];
      float4 wv = *(const float4*)(&ws[kk * FH + tx * 4]);
      #pragma unroll
      for (int i = 0; i < 8; ++i) {
        acc[i][0] += xv[i] * wv.x; acc[i][1] += xv[i] * wv.y;
        acc[i][2] += xv[i] * wv.z; acc[i][3] += xv[i] * wv.w;
      }
    }
    __syncthreads();
  }
  #pragma unroll
  for (int i = 0; i < 8; ++i) {
    int gr = row0 + ty * 8 + i;
    if (gr < N) {
      uint2 pk;
      pk.x = f2h(acc[i][0]) | (f2h(acc[i][1]) << 16);
      pk.y = f2h(acc[i][2]) | (f2h(acc[i][3]) << 16);
      *(uint2*)(H1h + (size_t)gr * FH + tx * 4) = pk;
    }
  }
}

// ---------------- GEMM2: H2[N,64](f32) = A1[N,128] @ W2[128,64]
__global__ __launch_bounds__(256) void gemm2_kernel(
    const float* __restrict__ A1, const float* __restrict__ W2,
    float* __restrict__ H2, int N) {
  __shared__ __align__(16) float xs[64][17];
  __shared__ __align__(16) float ws[16 * FO];
  int tid = threadIdx.x;
  int row0 = blockIdx.x * 64;
  int tx = tid & 15;        // cols tx*4..+3
  int ty = tid >> 4;        // rows ty*4..+3
  float acc[4][4];
  #pragma unroll
  for (int i = 0; i < 4; ++i)
    #pragma unroll
    for (int j = 0; j < 4; ++j) acc[i][j] = 0.f;

  for (int k0 = 0; k0 < FH; k0 += 16) {
    {
      int r = tid >> 2, kq = (tid & 3) * 4;
      int gr = row0 + r;
      float4 v = make_float4(0.f, 0.f, 0.f, 0.f);
      if (gr < N) v = *(const float4*)(A1 + (size_t)gr * FH + k0 + kq);
      xs[r][kq + 0] = v.x; xs[r][kq + 1] = v.y;
      xs[r][kq + 2] = v.z; xs[r][kq + 3] = v.w;
    }
    {
      const float4* s4 = (const float4*)(W2 + (size_t)k0 * FO);
      float4* d4 = (float4*)ws;
      d4[tid] = s4[tid];
    }
    __syncthreads();
    #pragma unroll
    for (int kk = 0; kk < 16; ++kk) {
      float xv[4];
      #pragma unroll
      for (int i = 0; i < 4; ++i) xv[i] = xs[ty * 4 + i][kk];
      float4 wv = *(const float4*)(&ws[kk * FO + tx * 4]);
      #pragma unroll
      for (int i = 0; i < 4; ++i) {
        acc[i][0] += xv[i] * wv.x; acc[i][1] += xv[i] * wv.y;
        acc[i][2] += xv[i] * wv.z; acc[i][3] += xv[i] * wv.w;
      }
    }
    __syncthreads();
  }
  #pragma unroll
  for (int i = 0; i < 4; ++i) {
    int gr = row0 + ty * 4 + i;
    if (gr < N) {
      float4 v = make_float4(acc[i][0], acc[i][1], acc[i][2], acc[i][3]);
      *(float4*)(H2 + (size_t)gr * FO + tx * 4) = v;
    }
  }
}

// ---------------- aggregation layer 1: a1 = relu(A @ h1 + b1), 128 fp16 feats
// one wave per node, wave-uniform edge loop (R1-proven structure), x2 unroll
__global__ __launch_bounds__(256) void agg1_kernel(
    const unsigned short* __restrict__ H1h, const int* __restrict__ ssrc,
    const float* __restrict__ snorm, const int* __restrict__ rowptr,
    const float* __restrict__ dinv, const float* __restrict__ b1,
    float* __restrict__ A1, int N) {
  int wid = (blockIdx.x * 256 + threadIdx.x) >> 6;
  int lane = threadIdx.x & 63;
  if (wid >= N) return;
  int p0 = rowptr[wid], p1 = rowptr[wid + 1];
  float ax0 = 0.f, ay0 = 0.f, ax1 = 0.f, ay1 = 0.f;
  int p = p0;
  for (; p + 2 <= p1; p += 2) {
    int s0 = ssrc[p], s1 = ssrc[p + 1];
    float n0 = snorm[p], n1 = snorm[p + 1];
    unsigned int h0 = *(const unsigned int*)(H1h + (size_t)s0 * FH + lane * 2);
    unsigned int h1 = *(const unsigned int*)(H1h + (size_t)s1 * FH + lane * 2);
    ax0 += n0 * h2f(h0 & 0xffffu);
    ay0 += n0 * h2f(h0 >> 16);
    ax1 += n1 * h2f(h1 & 0xffffu);
    ay1 += n1 * h2f(h1 >> 16);
  }
  if (p < p1) {
    int s0 = ssrc[p];
    float n0 = snorm[p];
    unsigned int h0 = *(const unsigned int*)(H1h + (size_t)s0 * FH + lane * 2);
    ax0 += n0 * h2f(h0 & 0xffffu);
    ay0 += n0 * h2f(h0 >> 16);
  }
  float di = dinv[wid], sn = di * di;
  unsigned int hs = *(const unsigned int*)(H1h + (size_t)wid * FH + lane * 2);
  ax0 += ax1 + sn * h2f(hs & 0xffffu);
  ay0 += ay1 + sn * h2f(hs >> 16);
  float2 bv = ((const float2*)b1)[lane];
  float2 o;
  o.x = fmaxf(ax0 + bv.x, 0.f);
  o.y = fmaxf(ay0 + bv.y, 0.f);
  *(float2*)(A1 + (size_t)wid * FH + 2 * lane) = o;
}

// ---------------- aggregation layer 2: out = A @ h2 + b2, 64 f32 feats
__global__ __launch_bounds__(256) void agg2_kernel(
    const float* __restrict__ H2, const int* __restrict__ ssrc,
    const float* __restrict__ snorm, const int* __restrict__ rowptr,
    const float* __restrict__ dinv, const float* __restrict__ b2,
    float* __restrict__ OUT, int N) {
  int wid = (blockIdx.x * 256 + threadIdx.x) >> 6;
  int lane = threadIdx.x & 63;
  if (wid >= N) return;
  int p0 = rowptr[wid], p1 = rowptr[wid + 1];
  float a0 = 0.f, a1v = 0.f;
  int p = p0;
  for (; p + 2 <= p1; p += 2) {
    int s0 = ssrc[p], s1 = ssrc[p + 1];
    float n0 = snorm[p], n1 = snorm[p + 1];
    a0  += n0 * H2[(size_t)s0 * FO + lane];
    a1v += n1 * H2[(size_t)s1 * FO + lane];
  }
  if (p < p1) {
    int s0 = ssrc[p];
    float n0 = snorm[p];
    a0 += n0 * H2[(size_t)s0 * FO + lane];
  }
  float di = dinv[wid];
  a0 += a1v + di * di * H2[(size_t)wid * FO + lane];
  a0 += b2[lane];
  OUT[(size_t)wid * FO + lane] = a0;
}

extern "C" void kernel_launch(void* const* d_in, const int* in_sizes, int n_in,
                              void* d_out, int out_size, void* d_ws, size_t ws_size,
                              hipStream_t stream) {
  const float* x  = (const float*)d_in[0];
  const int*   ei = (const int*)d_in[1];
  const float* ew = (const float*)d_in[2];
  const float* W1 = (const float*)d_in[3];
  const float* b1 = (const float*)d_in[4];
  const float* W2 = (const float*)d_in[5];
  const float* b2 = (const float*)d_in[6];
  float* out = (float*)d_out;

  const int N = in_sizes[0] / FIN;        // 100000
  const int E = in_sizes[2];              // 3200000
  const int* src = ei;
  const int* dst = ei + E;
  const int nb = (N + 1023) / 1024;       // scan blocks

  // workspace layout (16B-aligned slices), ~104MB total
  char* ws = (char*)d_ws;
  size_t off = 0;
  unsigned short* h1h = (unsigned short*)(ws + off); off += (size_t)N * FH * 2;  // fp16 h1
  float* h2     = (float*)h1h;            // f32 h2 aliases h1h (N*128*2 == N*64*4 bytes)
  float* a1     = (float*)(ws + off); off += (size_t)N * FH * 4;
  int*   ssrc   = (int*)  (ws + off); off += (size_t)E * 4;
  float* snorm  = (float*)(ws + off); off += (size_t)E * 4;
  int*   rowptr = (int*)  (ws + off); off += (((size_t)(N + 1) * 4) + 15) & ~(size_t)15;
  int*   cnt    = (int*)  (ws + off); off += (size_t)N * 4;
  float* degf   = (float*)(ws + off); off += (size_t)N * 4;
  int*   bsum   = (int*)  (ws + off); off += 1024;

  hipMemsetAsync(cnt, 0, (size_t)N * 8, stream);  // cnt + degf adjacent
  hist_kernel<<<(E + 255) / 256, 256, 0, stream>>>(src, dst, ew, cnt, degf, E);
  scan1_kernel<<<nb, 256, 0, stream>>>(cnt, rowptr, bsum, N);
  scan2_kernel<<<1, 256, 0, stream>>>(bsum, rowptr + N, nb, E);
  scan3_kernel<<<(N + 255) / 256, 256, 0, stream>>>(rowptr, bsum, N);
  dinv_kernel<<<(N + 255) / 256, 256, 0, stream>>>(degf, N);
  hipMemsetAsync(cnt, 0, (size_t)N * 4, stream);
  scatter_kernel<<<(E + 255) / 256, 256, 0, stream>>>(src, dst, ew, rowptr, cnt,
                                                      degf, ssrc, snorm, E);
  gemm1_kernel<<<(N + 63) / 64, 256, 0, stream>>>(x, W1, h1h, N);
  agg1_kernel<<<(N * 64 + 255) / 256, 256, 0, stream>>>(h1h, ssrc, snorm, rowptr,
                                                        degf, b1, a1, N);
  gemm2_kernel<<<(N + 63) / 64, 256, 0, stream>>>(a1, W2, h2, N);
  agg2_kernel<<<(N * 64 + 255) / 256, 256, 0, stream>>>(h2, ssrc, snorm, rowptr,
                                                        degf, b2, out, N);
}

// Round 5
// 648.471 us; speedup vs baseline: 2.1607x; 1.5203x over previous
//
#include <hip/hip_runtime.h>
#include <hip/hip_bf16.h>

// GCN 2-layer encoder: N=100000 nodes, E=3.2M edges, Fin=256, Fh=128, Fo=64.
//   h1 = x@W1 ; a1 = relu(A@h1 + b1) ; h2 = a1@W2 ; out = A@h2 + b2
// A includes self-loops (w=1), symmetric rsqrt-degree normalization.
//
// R5: single packed u64 atomic per edge replaces {cnt atomic, degf atomic,
// scatter-position atomic}: v = (1<<42) + (u64)(w * 2^30). High field =
// count (and returned old>>42 = stable in-row position), low field =
// fixed-point weighted degree (quant ~1e-9/edge, overflows only at
// deg>=4096 vs Poisson(32)). Scatter is then atomic-free. Edges stored
// int2{src, norm_bits}. Agg gather unroll x4. h1 fp16 / h2 f32 (R4-proven).

#define FIN 256
#define FH  128
#define FO  64

#define CNT_SHIFT 42
#define WSCALE 1073741824.0f          // 2^30
#define WINV   (1.0f / 1073741824.0f)
#define LOWMASK ((1ULL << CNT_SHIFT) - 1ULL)

__device__ __forceinline__ float h2f(unsigned int u16) {
  union { unsigned short s; _Float16 h; } c; c.s = (unsigned short)u16;
  return (float)c.h;
}
__device__ __forceinline__ unsigned int f2h(float f) {
  union { _Float16 h; unsigned short s; } c; c.h = (_Float16)f;  // RNE cvt
  return (unsigned int)c.s;
}

// ---------------- hist64: one u64 atomic per edge; returns stable position
__global__ __launch_bounds__(256) void hist64_kernel(
    const int* __restrict__ dst, const float* __restrict__ w,
    unsigned long long* __restrict__ cnt64, int* __restrict__ pos,
    int E) {
  int e = blockIdx.x * 256 + threadIdx.x;
  if (e < E) {
    int d = dst[e];
    unsigned long long v = (1ULL << CNT_SHIFT)
                         + (unsigned long long)(w[e] * WSCALE);
    unsigned long long old = atomicAdd(&cnt64[d], v);
    pos[e] = (int)(old >> CNT_SHIFT);
  }
}

// ---------------- 3-phase exclusive scan of cnt64>>42 -> rowptr; also dinv
__global__ __launch_bounds__(256) void scan1_kernel(
    const unsigned long long* __restrict__ cnt64, int* __restrict__ rowptr,
    int* __restrict__ bsum, float* __restrict__ dinv, int N) {
  __shared__ int tot[256];
  int t = threadIdx.x;
  int base = blockIdx.x * 1024 + t * 4;
  int v0 = 0, v1 = 0, v2 = 0, v3 = 0;
  #pragma unroll
  for (int q = 0; q < 4; ++q) {
    int idx = base + q;
    if (idx < N) {
      unsigned long long c = cnt64[idx];
      int cv = (int)(c >> CNT_SHIFT);
      float deg = (float)(c & LOWMASK) * WINV;
      dinv[idx] = rsqrtf(1.0f + deg);
      if (q == 0) v0 = cv; else if (q == 1) v1 = cv;
      else if (q == 2) v2 = cv; else v3 = cv;
    }
  }
  int s = v0 + v1 + v2 + v3;
  tot[t] = s;
  __syncthreads();
  for (int off = 1; off < 256; off <<= 1) {
    int y = (t >= off) ? tot[t - off] : 0;
    __syncthreads();
    tot[t] += y;
    __syncthreads();
  }
  int p = tot[t] - s;  // exclusive within block
  if (t == 255) bsum[blockIdx.x] = tot[255];
  if (base + 0 < N) rowptr[base + 0] = p; p += v0;
  if (base + 1 < N) rowptr[base + 1] = p; p += v1;
  if (base + 2 < N) rowptr[base + 2] = p; p += v2;
  if (base + 3 < N) rowptr[base + 3] = p;
}

__global__ __launch_bounds__(256) void scan2_kernel(
    int* __restrict__ bsum, int* __restrict__ rowptrN, int nb, int E) {
  __shared__ int buf[256];
  int t = threadIdx.x;
  int v = (t < nb) ? bsum[t] : 0;
  buf[t] = v;
  __syncthreads();
  for (int off = 1; off < 256; off <<= 1) {
    int y = (t >= off) ? buf[t - off] : 0;
    __syncthreads();
    buf[t] += y;
    __syncthreads();
  }
  if (t < nb) bsum[t] = buf[t] - v;  // exclusive
  if (t == 0) rowptrN[0] = E;
}

__global__ __launch_bounds__(256) void scan3_kernel(
    int* __restrict__ rowptr, const int* __restrict__ bsum, int N) {
  int i = blockIdx.x * 256 + threadIdx.x;
  if (i < N) rowptr[i] += bsum[i >> 10];
}

// ---------------- scatter (atomic-free): edges[rowptr[d]+pos[e]] = {src, norm}
__global__ __launch_bounds__(256) void scatter_kernel(
    const int* __restrict__ src, const int* __restrict__ dst,
    const float* __restrict__ w, const int* __restrict__ rowptr,
    const int* __restrict__ pos, const float* __restrict__ dinv,
    int2* __restrict__ edges, int E) {
  int e = blockIdx.x * 256 + threadIdx.x;
  if (e < E) {
    int s = src[e], d = dst[e];
    float nm = dinv[s] * w[e] * dinv[d];
    edges[rowptr[d] + pos[e]] = make_int2(s, __float_as_int(nm));
  }
}

// ---------------- GEMM1: H1h[N,128](fp16) = X[N,256] @ W[256,128]
__global__ __launch_bounds__(256) void gemm1_kernel(
    const float* __restrict__ X, const float* __restrict__ W,
    unsigned short* __restrict__ H1h, int N) {
  __shared__ __align__(16) float xs[64][17];
  __shared__ __align__(16) float ws[16 * FH];
  int tid = threadIdx.x;
  int row0 = blockIdx.x * 64;
  int tx = tid & 31;        // cols tx*4 .. +3
  int ty = tid >> 5;        // rows ty*8 .. +7
  float acc[8][4];
  #pragma unroll
  for (int i = 0; i < 8; ++i)
    #pragma unroll
    for (int j = 0; j < 4; ++j) acc[i][j] = 0.f;

  for (int k0 = 0; k0 < FIN; k0 += 16) {
    {
      int r = tid >> 2, kq = (tid & 3) * 4;
      int gr = row0 + r;
      float4 v = make_float4(0.f, 0.f, 0.f, 0.f);
      if (gr < N) v = *(const float4*)(X + (size_t)gr * FIN + k0 + kq);
      xs[r][kq + 0] = v.x; xs[r][kq + 1] = v.y;
      xs[r][kq + 2] = v.z; xs[r][kq + 3] = v.w;
    }
    {
      const float4* s4 = (const float4*)(W + (size_t)k0 * FH);
      float4* d4 = (float4*)ws;
      d4[tid] = s4[tid];
      d4[tid + 256] = s4[tid + 256];
    }
    __syncthreads();
    #pragma unroll
    for (int kk = 0; kk < 16; ++kk) {
      float xv[8];
      #pragma unroll
      for (int i = 0; i < 8; ++i) xv[i] = xs[ty * 8 + i][kk];
      float4 wv = *(const float4*)(&ws[kk * FH + tx * 4]);
      #pragma unroll
      for (int i = 0; i < 8; ++i) {
        acc[i][0] += xv[i] * wv.x; acc[i][1] += xv[i] * wv.y;
        acc[i][2] += xv[i] * wv.z; acc[i][3] += xv[i] * wv.w;
      }
    }
    __syncthreads();
  }
  #pragma unroll
  for (int i = 0; i < 8; ++i) {
    int gr = row0 + ty * 8 + i;
    if (gr < N) {
      uint2 pk;
      pk.x = f2h(acc[i][0]) | (f2h(acc[i][1]) << 16);
      pk.y = f2h(acc[i][2]) | (f2h(acc[i][3]) << 16);
      *(uint2*)(H1h + (size_t)gr * FH + tx * 4) = pk;
    }
  }
}

// ---------------- GEMM2: H2[N,64](f32) = A1[N,128] @ W2[128,64]
__global__ __launch_bounds__(256) void gemm2_kernel(
    const float* __restrict__ A1, const float* __restrict__ W2,
    float* __restrict__ H2, int N) {
  __shared__ __align__(16) float xs[64][17];
  __shared__ __align__(16) float ws[16 * FO];
  int tid = threadIdx.x;
  int row0 = blockIdx.x * 64;
  int tx = tid & 15;        // cols tx*4..+3
  int ty = tid >> 4;        // rows ty*4..+3
  float acc[4][4];
  #pragma unroll
  for (int i = 0; i < 4; ++i)
    #pragma unroll
    for (int j = 0; j < 4; ++j) acc[i][j] = 0.f;

  for (int k0 = 0; k0 < FH; k0 += 16) {
    {
      int r = tid >> 2, kq = (tid & 3) * 4;
      int gr = row0 + r;
      float4 v = make_float4(0.f, 0.f, 0.f, 0.f);
      if (gr < N) v = *(const float4*)(A1 + (size_t)gr * FH + k0 + kq);
      xs[r][kq + 0] = v.x; xs[r][kq + 1] = v.y;
      xs[r][kq + 2] = v.z; xs[r][kq + 3] = v.w;
    }
    {
      const float4* s4 = (const float4*)(W2 + (size_t)k0 * FO);
      float4* d4 = (float4*)ws;
      d4[tid] = s4[tid];
    }
    __syncthreads();
    #pragma unroll
    for (int kk = 0; kk < 16; ++kk) {
      float xv[4];
      #pragma unroll
      for (int i = 0; i < 4; ++i) xv[i] = xs[ty * 4 + i][kk];
      float4 wv = *(const float4*)(&ws[kk * FO + tx * 4]);
      #pragma unroll
      for (int i = 0; i < 4; ++i) {
        acc[i][0] += xv[i] * wv.x; acc[i][1] += xv[i] * wv.y;
        acc[i][2] += xv[i] * wv.z; acc[i][3] += xv[i] * wv.w;
      }
    }
    __syncthreads();
  }
  #pragma unroll
  for (int i = 0; i < 4; ++i) {
    int gr = row0 + ty * 4 + i;
    if (gr < N) {
      float4 v = make_float4(acc[i][0], acc[i][1], acc[i][2], acc[i][3]);
      *(float4*)(H2 + (size_t)gr * FO + tx * 4) = v;
    }
  }
}

// ---------------- aggregation layer 1: a1 = relu(A @ h1 + b1), 128 fp16 feats
// one wave per node, wave-uniform edge loop (R4-proven structure), x4 unroll
__global__ __launch_bounds__(256) void agg1_kernel(
    const unsigned short* __restrict__ H1h, const int2* __restrict__ edges,
    const int* __restrict__ rowptr, const float* __restrict__ dinv,
    const float* __restrict__ b1, float* __restrict__ A1, int N) {
  int wid = (blockIdx.x * 256 + threadIdx.x) >> 6;
  int lane = threadIdx.x & 63;
  if (wid >= N) return;
  int p0 = rowptr[wid], p1 = rowptr[wid + 1];
  float ax0 = 0.f, ay0 = 0.f, ax1 = 0.f, ay1 = 0.f;
  float ax2 = 0.f, ay2 = 0.f, ax3 = 0.f, ay3 = 0.f;
  int p = p0;
  for (; p + 4 <= p1; p += 4) {
    int2 e0 = edges[p], e1 = edges[p + 1], e2 = edges[p + 2], e3 = edges[p + 3];
    unsigned int h0 = *(const unsigned int*)(H1h + (size_t)e0.x * FH + lane * 2);
    unsigned int h1 = *(const unsigned int*)(H1h + (size_t)e1.x * FH + lane * 2);
    unsigned int h2 = *(const unsigned int*)(H1h + (size_t)e2.x * FH + lane * 2);
    unsigned int h3 = *(const unsigned int*)(H1h + (size_t)e3.x * FH + lane * 2);
    float n0 = __int_as_float(e0.y), n1 = __int_as_float(e1.y);
    float n2 = __int_as_float(e2.y), n3 = __int_as_float(e3.y);
    ax0 += n0 * h2f(h0 & 0xffffu); ay0 += n0 * h2f(h0 >> 16);
    ax1 += n1 * h2f(h1 & 0xffffu); ay1 += n1 * h2f(h1 >> 16);
    ax2 += n2 * h2f(h2 & 0xffffu); ay2 += n2 * h2f(h2 >> 16);
    ax3 += n3 * h2f(h3 & 0xffffu); ay3 += n3 * h2f(h3 >> 16);
  }
  for (; p < p1; ++p) {
    int2 e0 = edges[p];
    float n0 = __int_as_float(e0.y);
    unsigned int h0 = *(const unsigned int*)(H1h + (size_t)e0.x * FH + lane * 2);
    ax0 += n0 * h2f(h0 & 0xffffu); ay0 += n0 * h2f(h0 >> 16);
  }
  float di = dinv[wid], sn = di * di;
  unsigned int hs = *(const unsigned int*)(H1h + (size_t)wid * FH + lane * 2);
  float ax = (ax0 + ax1) + (ax2 + ax3) + sn * h2f(hs & 0xffffu);
  float ay = (ay0 + ay1) + (ay2 + ay3) + sn * h2f(hs >> 16);
  float2 bv = ((const float2*)b1)[lane];
  float2 o;
  o.x = fmaxf(ax + bv.x, 0.f);
  o.y = fmaxf(ay + bv.y, 0.f);
  *(float2*)(A1 + (size_t)wid * FH + 2 * lane) = o;
}

// ---------------- aggregation layer 2: out = A @ h2 + b2, 64 f32 feats
__global__ __launch_bounds__(256) void agg2_kernel(
    const float* __restrict__ H2, const int2* __restrict__ edges,
    const int* __restrict__ rowptr, const float* __restrict__ dinv,
    const float* __restrict__ b2, float* __restrict__ OUT, int N) {
  int wid = (blockIdx.x * 256 + threadIdx.x) >> 6;
  int lane = threadIdx.x & 63;
  if (wid >= N) return;
  int p0 = rowptr[wid], p1 = rowptr[wid + 1];
  float a0 = 0.f, a1v = 0.f, a2 = 0.f, a3 = 0.f;
  int p = p0;
  for (; p + 4 <= p1; p += 4) {
    int2 e0 = edges[p], e1 = edges[p + 1], e2 = edges[p + 2], e3 = edges[p + 3];
    float v0 = H2[(size_t)e0.x * FO + lane];
    float v1 = H2[(size_t)e1.x * FO + lane];
    float v2 = H2[(size_t)e2.x * FO + lane];
    float v3 = H2[(size_t)e3.x * FO + lane];
    a0  += __int_as_float(e0.y) * v0;
    a1v += __int_as_float(e1.y) * v1;
    a2  += __int_as_float(e2.y) * v2;
    a3  += __int_as_float(e3.y) * v3;
  }
  for (; p < p1; ++p) {
    int2 e0 = edges[p];
    a0 += __int_as_float(e0.y) * H2[(size_t)e0.x * FO + lane];
  }
  float di = dinv[wid];
  float r = (a0 + a1v) + (a2 + a3) + di * di * H2[(size_t)wid * FO + lane];
  r += b2[lane];
  OUT[(size_t)wid * FO + lane] = r;
}

extern "C" void kernel_launch(void* const* d_in, const int* in_sizes, int n_in,
                              void* d_out, int out_size, void* d_ws, size_t ws_size,
                              hipStream_t stream) {
  const float* x  = (const float*)d_in[0];
  const int*   ei = (const int*)d_in[1];
  const float* ew = (const float*)d_in[2];
  const float* W1 = (const float*)d_in[3];
  const float* b1 = (const float*)d_in[4];
  const float* W2 = (const float*)d_in[5];
  const float* b2 = (const float*)d_in[6];
  float* out = (float*)d_out;

  const int N = in_sizes[0] / FIN;        // 100000
  const int E = in_sizes[2];              // 3200000
  const int* src = ei;
  const int* dst = ei + E;
  const int nb = (N + 1023) / 1024;       // scan blocks

  // workspace layout (16B-aligned slices), ~117MB total
  char* ws = (char*)d_ws;
  size_t off = 0;
  unsigned short* h1h = (unsigned short*)(ws + off); off += (size_t)N * FH * 2;  // fp16 h1
  float* h2     = (float*)h1h;            // f32 h2 aliases h1h (N*128*2 == N*64*4 bytes)
  float* a1     = (float*)(ws + off); off += (size_t)N * FH * 4;
  int2*  edges  = (int2*) (ws + off); off += (size_t)E * 8;
  int*   pos    = (int*)  (ws + off); off += (size_t)E * 4;
  unsigned long long* cnt64 = (unsigned long long*)(ws + off); off += (size_t)N * 8;
  int*   rowptr = (int*)  (ws + off); off += (((size_t)(N + 1) * 4) + 15) & ~(size_t)15;
  float* dinv   = (float*)(ws + off); off += (size_t)N * 4;
  int*   bsum   = (int*)  (ws + off); off += 1024;

  hipMemsetAsync(cnt64, 0, (size_t)N * 8, stream);
  hist64_kernel<<<(E + 255) / 256, 256, 0, stream>>>(dst, ew, cnt64, pos, E);
  scan1_kernel<<<nb, 256, 0, stream>>>(cnt64, rowptr, bsum, dinv, N);
  scan2_kernel<<<1, 256, 0, stream>>>(bsum, rowptr + N, nb, E);
  scan3_kernel<<<(N + 255) / 256, 256, 0, stream>>>(rowptr, bsum, N);
  scatter_kernel<<<(E + 255) / 256, 256, 0, stream>>>(src, dst, ew, rowptr, pos,
                                                      dinv, edges, E);
  gemm1_kernel<<<(N + 63) / 64, 256, 0, stream>>>(x, W1, h1h, N);
  agg1_kernel<<<(N * 64 + 255) / 256, 256, 0, stream>>>(h1h, edges, rowptr,
                                                        dinv, b1, a1, N);
  gemm2_kernel<<<(N + 63) / 64, 256, 0, stream>>>(a1, W2, h2, N);
  agg2_kernel<<<(N * 64 + 255) / 256, 256, 0, stream>>>(h2, edges, rowptr,
                                                        dinv, b2, out, N);
}

// Round 6
// 580.083 us; speedup vs baseline: 2.4154x; 1.1179x over previous
//
#include <hip/hip_runtime.h>
#include <hip/hip_bf16.h>

// GCN 2-layer encoder: N=100000 nodes, E=3.2M edges, Fin=256, Fh=128, Fo=64.
//   h1 = x@W1 ; a1 = relu(A@h1 + b1) ; h2 = a1@W2 ; out = A@h2 + b2
// A includes self-loops (w=1), symmetric rsqrt-degree normalization.
//
// R6: (a) gemm1 fused into hist64 as heterogeneous blocks — hist is
// atomic-bound (VALUBusy 0.9%, atomics write through to HBM at ~21G/s),
// gemm1 is VALU-bound and independent; fused time ~= max of the two.
// (b) h2 stored fp16 (error ~2e-5 at output; R4 proved fp16-h1 adds zero
// visible error) -> agg2 gather bytes halve. h1 fp16, CSR via packed-u64
// atomic (count | fixed-point wdeg; returned old>>42 = stable position).

#define FIN 256
#define FH  128
#define FO  64

#define CNT_SHIFT 42
#define WSCALE 1073741824.0f          // 2^30
#define WINV   (1.0f / 1073741824.0f)
#define LOWMASK ((1ULL << CNT_SHIFT) - 1ULL)

__device__ __forceinline__ float h2f(unsigned int u16) {
  union { unsigned short s; _Float16 h; } c; c.s = (unsigned short)u16;
  return (float)c.h;
}
__device__ __forceinline__ unsigned int f2h(float f) {
  union { _Float16 h; unsigned short s; } c; c.h = (_Float16)f;  // RNE cvt
  return (unsigned int)c.s;
}

// ---------------- fused: blocks [0,NBG) gemm1, blocks [NBG,..) hist64
__global__ __launch_bounds__(256) void hist_gemm1_kernel(
    const int* __restrict__ dst, const float* __restrict__ w,
    unsigned long long* __restrict__ cnt64, int* __restrict__ pos, int E,
    const float* __restrict__ X, const float* __restrict__ W,
    unsigned short* __restrict__ H1h, int N, int NBG) {
  __shared__ __align__(16) float xs[64][17];
  __shared__ __align__(16) float wsm[16 * FH];
  int bid = blockIdx.x;
  int tid = threadIdx.x;
  if (bid >= NBG) {
    // ---- histogram part: one u64 atomic per edge; returns stable position
    int e = (bid - NBG) * 256 + tid;
    if (e < E) {
      int d = dst[e];
      unsigned long long v = (1ULL << CNT_SHIFT)
                           + (unsigned long long)(w[e] * WSCALE);
      unsigned long long old = atomicAdd(&cnt64[d], v);
      pos[e] = (int)(old >> CNT_SHIFT);
    }
    return;
  }
  // ---- gemm1 part: H1h[64 rows, 128 cols] fp16 = X @ W1
  int row0 = bid * 64;
  int tx = tid & 31;        // cols tx*4 .. +3
  int ty = tid >> 5;        // rows ty*8 .. +7
  float acc[8][4];
  #pragma unroll
  for (int i = 0; i < 8; ++i)
    #pragma unroll
    for (int j = 0; j < 4; ++j) acc[i][j] = 0.f;

  for (int k0 = 0; k0 < FIN; k0 += 16) {
    {
      int r = tid >> 2, kq = (tid & 3) * 4;
      int gr = row0 + r;
      float4 v = make_float4(0.f, 0.f, 0.f, 0.f);
      if (gr < N) v = *(const float4*)(X + (size_t)gr * FIN + k0 + kq);
      xs[r][kq + 0] = v.x; xs[r][kq + 1] = v.y;
      xs[r][kq + 2] = v.z; xs[r][kq + 3] = v.w;
    }
    {
      const float4* s4 = (const float4*)(W + (size_t)k0 * FH);
      float4* d4 = (float4*)wsm;
      d4[tid] = s4[tid];
      d4[tid + 256] = s4[tid + 256];
    }
    __syncthreads();
    #pragma unroll
    for (int kk = 0; kk < 16; ++kk) {
      float xv[8];
      #pragma unroll
      for (int i = 0; i < 8; ++i) xv[i] = xs[ty * 8 + i][kk];
      float4 wv = *(const float4*)(&wsm[kk * FH + tx * 4]);
      #pragma unroll
      for (int i = 0; i < 8; ++i) {
        acc[i][0] += xv[i] * wv.x; acc[i][1] += xv[i] * wv.y;
        acc[i][2] += xv[i] * wv.z; acc[i][3] += xv[i] * wv.w;
      }
    }
    __syncthreads();
  }
  #pragma unroll
  for (int i = 0; i < 8; ++i) {
    int gr = row0 + ty * 8 + i;
    if (gr < N) {
      uint2 pk;
      pk.x = f2h(acc[i][0]) | (f2h(acc[i][1]) << 16);
      pk.y = f2h(acc[i][2]) | (f2h(acc[i][3]) << 16);
      *(uint2*)(H1h + (size_t)gr * FH + tx * 4) = pk;
    }
  }
}

// ---------------- 3-phase exclusive scan of cnt64>>42 -> rowptr; also dinv
__global__ __launch_bounds__(256) void scan1_kernel(
    const unsigned long long* __restrict__ cnt64, int* __restrict__ rowptr,
    int* __restrict__ bsum, float* __restrict__ dinv, int N) {
  __shared__ int tot[256];
  int t = threadIdx.x;
  int base = blockIdx.x * 1024 + t * 4;
  int v0 = 0, v1 = 0, v2 = 0, v3 = 0;
  #pragma unroll
  for (int q = 0; q < 4; ++q) {
    int idx = base + q;
    if (idx < N) {
      unsigned long long c = cnt64[idx];
      int cv = (int)(c >> CNT_SHIFT);
      float deg = (float)(c & LOWMASK) * WINV;
      dinv[idx] = rsqrtf(1.0f + deg);
      if (q == 0) v0 = cv; else if (q == 1) v1 = cv;
      else if (q == 2) v2 = cv; else v3 = cv;
    }
  }
  int s = v0 + v1 + v2 + v3;
  tot[t] = s;
  __syncthreads();
  for (int off = 1; off < 256; off <<= 1) {
    int y = (t >= off) ? tot[t - off] : 0;
    __syncthreads();
    tot[t] += y;
    __syncthreads();
  }
  int p = tot[t] - s;  // exclusive within block
  if (t == 255) bsum[blockIdx.x] = tot[255];
  if (base + 0 < N) rowptr[base + 0] = p; p += v0;
  if (base + 1 < N) rowptr[base + 1] = p; p += v1;
  if (base + 2 < N) rowptr[base + 2] = p; p += v2;
  if (base + 3 < N) rowptr[base + 3] = p;
}

__global__ __launch_bounds__(256) void scan2_kernel(
    int* __restrict__ bsum, int* __restrict__ rowptrN, int nb, int E) {
  __shared__ int buf[256];
  int t = threadIdx.x;
  int v = (t < nb) ? bsum[t] : 0;
  buf[t] = v;
  __syncthreads();
  for (int off = 1; off < 256; off <<= 1) {
    int y = (t >= off) ? buf[t - off] : 0;
    __syncthreads();
    buf[t] += y;
    __syncthreads();
  }
  if (t < nb) bsum[t] = buf[t] - v;  // exclusive
  if (t == 0) rowptrN[0] = E;
}

__global__ __launch_bounds__(256) void scan3_kernel(
    int* __restrict__ rowptr, const int* __restrict__ bsum, int N) {
  int i = blockIdx.x * 256 + threadIdx.x;
  if (i < N) rowptr[i] += bsum[i >> 10];
}

// ---------------- scatter (atomic-free): edges[rowptr[d]+pos[e]] = {src, norm}
__global__ __launch_bounds__(256) void scatter_kernel(
    const int* __restrict__ src, const int* __restrict__ dst,
    const float* __restrict__ w, const int* __restrict__ rowptr,
    const int* __restrict__ pos, const float* __restrict__ dinv,
    int2* __restrict__ edges, int E) {
  int e = blockIdx.x * 256 + threadIdx.x;
  if (e < E) {
    int s = src[e], d = dst[e];
    float nm = dinv[s] * w[e] * dinv[d];
    edges[rowptr[d] + pos[e]] = make_int2(s, __float_as_int(nm));
  }
}

// ---------------- GEMM2: H2h[N,64](fp16) = A1[N,128] @ W2[128,64]
__global__ __launch_bounds__(256) void gemm2_kernel(
    const float* __restrict__ A1, const float* __restrict__ W2,
    unsigned short* __restrict__ H2h, int N) {
  __shared__ __align__(16) float xs[64][17];
  __shared__ __align__(16) float ws[16 * FO];
  int tid = threadIdx.x;
  int row0 = blockIdx.x * 64;
  int tx = tid & 15;        // cols tx*4..+3
  int ty = tid >> 4;        // rows ty*4..+3
  float acc[4][4];
  #pragma unroll
  for (int i = 0; i < 4; ++i)
    #pragma unroll
    for (int j = 0; j < 4; ++j) acc[i][j] = 0.f;

  for (int k0 = 0; k0 < FH; k0 += 16) {
    {
      int r = tid >> 2, kq = (tid & 3) * 4;
      int gr = row0 + r;
      float4 v = make_float4(0.f, 0.f, 0.f, 0.f);
      if (gr < N) v = *(const float4*)(A1 + (size_t)gr * FH + k0 + kq);
      xs[r][kq + 0] = v.x; xs[r][kq + 1] = v.y;
      xs[r][kq + 2] = v.z; xs[r][kq + 3] = v.w;
    }
    {
      const float4* s4 = (const float4*)(W2 + (size_t)k0 * FO);
      float4* d4 = (float4*)ws;
      d4[tid] = s4[tid];
    }
    __syncthreads();
    #pragma unroll
    for (int kk = 0; kk < 16; ++kk) {
      float xv[4];
      #pragma unroll
      for (int i = 0; i < 4; ++i) xv[i] = xs[ty * 4 + i][kk];
      float4 wv = *(const float4*)(&ws[kk * FO + tx * 4]);
      #pragma unroll
      for (int i = 0; i < 4; ++i) {
        acc[i][0] += xv[i] * wv.x; acc[i][1] += xv[i] * wv.y;
        acc[i][2] += xv[i] * wv.z; acc[i][3] += xv[i] * wv.w;
      }
    }
    __syncthreads();
  }
  #pragma unroll
  for (int i = 0; i < 4; ++i) {
    int gr = row0 + ty * 4 + i;
    if (gr < N) {
      uint2 pk;
      pk.x = f2h(acc[i][0]) | (f2h(acc[i][1]) << 16);
      pk.y = f2h(acc[i][2]) | (f2h(acc[i][3]) << 16);
      *(uint2*)(H2h + (size_t)gr * FO + tx * 4) = pk;
    }
  }
}

// ---------------- aggregation layer 1: a1 = relu(A @ h1 + b1), 128 fp16 feats
// one wave per node, wave-uniform edge loop, x4 unroll
__global__ __launch_bounds__(256) void agg1_kernel(
    const unsigned short* __restrict__ H1h, const int2* __restrict__ edges,
    const int* __restrict__ rowptr, const float* __restrict__ dinv,
    const float* __restrict__ b1, float* __restrict__ A1, int N) {
  int wid = (blockIdx.x * 256 + threadIdx.x) >> 6;
  int lane = threadIdx.x & 63;
  if (wid >= N) return;
  int p0 = rowptr[wid], p1 = rowptr[wid + 1];
  float ax0 = 0.f, ay0 = 0.f, ax1 = 0.f, ay1 = 0.f;
  float ax2 = 0.f, ay2 = 0.f, ax3 = 0.f, ay3 = 0.f;
  int p = p0;
  for (; p + 4 <= p1; p += 4) {
    int2 e0 = edges[p], e1 = edges[p + 1], e2 = edges[p + 2], e3 = edges[p + 3];
    unsigned int h0 = *(const unsigned int*)(H1h + (size_t)e0.x * FH + lane * 2);
    unsigned int h1 = *(const unsigned int*)(H1h + (size_t)e1.x * FH + lane * 2);
    unsigned int h2 = *(const unsigned int*)(H1h + (size_t)e2.x * FH + lane * 2);
    unsigned int h3 = *(const unsigned int*)(H1h + (size_t)e3.x * FH + lane * 2);
    float n0 = __int_as_float(e0.y), n1 = __int_as_float(e1.y);
    float n2 = __int_as_float(e2.y), n3 = __int_as_float(e3.y);
    ax0 += n0 * h2f(h0 & 0xffffu); ay0 += n0 * h2f(h0 >> 16);
    ax1 += n1 * h2f(h1 & 0xffffu); ay1 += n1 * h2f(h1 >> 16);
    ax2 += n2 * h2f(h2 & 0xffffu); ay2 += n2 * h2f(h2 >> 16);
    ax3 += n3 * h2f(h3 & 0xffffu); ay3 += n3 * h2f(h3 >> 16);
  }
  for (; p < p1; ++p) {
    int2 e0 = edges[p];
    float n0 = __int_as_float(e0.y);
    unsigned int h0 = *(const unsigned int*)(H1h + (size_t)e0.x * FH + lane * 2);
    ax0 += n0 * h2f(h0 & 0xffffu); ay0 += n0 * h2f(h0 >> 16);
  }
  float di = dinv[wid], sn = di * di;
  unsigned int hs = *(const unsigned int*)(H1h + (size_t)wid * FH + lane * 2);
  float ax = (ax0 + ax1) + (ax2 + ax3) + sn * h2f(hs & 0xffffu);
  float ay = (ay0 + ay1) + (ay2 + ay3) + sn * h2f(hs >> 16);
  float2 bv = ((const float2*)b1)[lane];
  float2 o;
  o.x = fmaxf(ax + bv.x, 0.f);
  o.y = fmaxf(ay + bv.y, 0.f);
  *(float2*)(A1 + (size_t)wid * FH + 2 * lane) = o;
}

// ---------------- aggregation layer 2: out = A @ h2 + b2, 64 fp16 feats
__global__ __launch_bounds__(256) void agg2_kernel(
    const unsigned short* __restrict__ H2h, const int2* __restrict__ edges,
    const int* __restrict__ rowptr, const float* __restrict__ dinv,
    const float* __restrict__ b2, float* __restrict__ OUT, int N) {
  int wid = (blockIdx.x * 256 + threadIdx.x) >> 6;
  int lane = threadIdx.x & 63;
  if (wid >= N) return;
  int p0 = rowptr[wid], p1 = rowptr[wid + 1];
  float a0 = 0.f, a1v = 0.f, a2 = 0.f, a3 = 0.f;
  int p = p0;
  for (; p + 4 <= p1; p += 4) {
    int2 e0 = edges[p], e1 = edges[p + 1], e2 = edges[p + 2], e3 = edges[p + 3];
    float v0 = h2f(H2h[(size_t)e0.x * FO + lane]);
    float v1 = h2f(H2h[(size_t)e1.x * FO + lane]);
    float v2 = h2f(H2h[(size_t)e2.x * FO + lane]);
    float v3 = h2f(H2h[(size_t)e3.x * FO + lane]);
    a0  += __int_as_float(e0.y) * v0;
    a1v += __int_as_float(e1.y) * v1;
    a2  += __int_as_float(e2.y) * v2;
    a3  += __int_as_float(e3.y) * v3;
  }
  for (; p < p1; ++p) {
    int2 e0 = edges[p];
    a0 += __int_as_float(e0.y) * h2f(H2h[(size_t)e0.x * FO + lane]);
  }
  float di = dinv[wid];
  float r = (a0 + a1v) + (a2 + a3) + di * di * h2f(H2h[(size_t)wid * FO + lane]);
  r += b2[lane];
  OUT[(size_t)wid * FO + lane] = r;
}

extern "C" void kernel_launch(void* const* d_in, const int* in_sizes, int n_in,
                              void* d_out, int out_size, void* d_ws, size_t ws_size,
                              hipStream_t stream) {
  const float* x  = (const float*)d_in[0];
  const int*   ei = (const int*)d_in[1];
  const float* ew = (const float*)d_in[2];
  const float* W1 = (const float*)d_in[3];
  const float* b1 = (const float*)d_in[4];
  const float* W2 = (const float*)d_in[5];
  const float* b2 = (const float*)d_in[6];
  float* out = (float*)d_out;

  const int N = in_sizes[0] / FIN;        // 100000
  const int E = in_sizes[2];              // 3200000
  const int* src = ei;
  const int* dst = ei + E;
  const int nb = (N + 1023) / 1024;       // scan blocks
  const int NBG = (N + 63) / 64;          // gemm1 blocks
  const int NBH = (E + 255) / 256;        // hist blocks

  // workspace layout (16B-aligned slices), ~105MB total
  char* ws = (char*)d_ws;
  size_t off = 0;
  unsigned short* h1h = (unsigned short*)(ws + off); off += (size_t)N * FH * 2;  // fp16 h1
  unsigned short* h2h = (unsigned short*)(ws + off); off += (size_t)N * FO * 2;  // fp16 h2
  float* a1     = (float*)(ws + off); off += (size_t)N * FH * 4;
  int2*  edges  = (int2*) (ws + off); off += (size_t)E * 8;
  int*   pos    = (int*)  (ws + off); off += (size_t)E * 4;
  unsigned long long* cnt64 = (unsigned long long*)(ws + off); off += (size_t)N * 8;
  int*   rowptr = (int*)  (ws + off); off += (((size_t)(N + 1) * 4) + 15) & ~(size_t)15;
  float* dinv   = (float*)(ws + off); off += (size_t)N * 4;
  int*   bsum   = (int*)  (ws + off); off += 1024;

  hipMemsetAsync(cnt64, 0, (size_t)N * 8, stream);
  hist_gemm1_kernel<<<NBG + NBH, 256, 0, stream>>>(dst, ew, cnt64, pos, E,
                                                   x, W1, h1h, N, NBG);
  scan1_kernel<<<nb, 256, 0, stream>>>(cnt64, rowptr, bsum, dinv, N);
  scan2_kernel<<<1, 256, 0, stream>>>(bsum, rowptr + N, nb, E);
  scan3_kernel<<<(N + 255) / 256, 256, 0, stream>>>(rowptr, bsum, N);
  scatter_kernel<<<(E + 255) / 256, 256, 0, stream>>>(src, dst, ew, rowptr, pos,
                                                      dinv, edges, E);
  agg1_kernel<<<(N * 64 + 255) / 256, 256, 0, stream>>>(h1h, edges, rowptr,
                                                        dinv, b1, a1, N);
  gemm2_kernel<<<(N + 63) / 64, 256, 0, stream>>>(a1, W2, h2h, N);
  agg2_kernel<<<(N * 64 + 255) / 256, 256, 0, stream>>>(h2h, edges, rowptr,
                                                        dinv, b2, out, N);
}